// Round 9
// baseline (655.124 us; speedup 1.0000x reference)
//
#include <hip/hip_runtime.h>
#include <hip/hip_bf16.h>
#include <cstdint>
#include <cstddef>

// ---------------------------------------------------------------------------
// ChildSumTreeLSTM, complete binary tree N=131071=2^17-1, dim 256.
// Round 13: r12 structure (649.3 us) + three additive changes:
//  (1) leaf_gemm reads f32 X directly (reg-staged A: float4 x2 -> cvt ->
//      ds_write_b128 with the SAME lane->LDS slot as GLD16, so MFMA-side
//      swizzle unchanged). Internal levels only read Xb rows [0,65535) ->
//  (2) prep_all converts ONLY internal X rows (-67 MB read, -34 MB write,
//      ~-18 us serial prefix; leaf no longer waits on leaf-row conversion).
//  (3) Wiou pre-packed to tile order [bx][96][512]: B staging for leaf /
//      lvl15-iou / fused-IOU becomes linear (bx*96+rb)*512 -- removes the
//      3-section row scatter + per-issue address VALU on the hottest operand.
// r12 post-mortem note: FUSE_TOP 13->14 was ~neutral -> fused kernel's 2
// blocks/CU (80 KB LDS) efficiency loss cancels dispatch savings at big
// counts; occupancy split is the next lever if this round's gain is small.
//   fused LDS: 32+4+16+12+16 = 80 KB static; acc 80 VGPR (F 32 + IOU 48)
// ---------------------------------------------------------------------------

typedef __bf16 bf16;
typedef bf16 bf16x8 __attribute__((ext_vector_type(8)));
typedef float f32x4 __attribute__((ext_vector_type(4)));

#define LEAF_START 65535
#define LEAF_COUNT 65536
#define FUSE_TOP   14     // levels FUSE_TOP..0 use the fused one-dispatch-per-level kernel

// async global->LDS, 16 B per lane, dest = base + lane*16
#define GLD16(g, l) __builtin_amdgcn_global_load_lds(                         \
    (const __attribute__((address_space(1))) void*)(g),                       \
    (__attribute__((address_space(3))) void*)(l), 16, 0, 0)

// c = sig(i)*tanh(u) + fc ; h = sig(o)*tanh(c).  Merged: 6 trans + ~8 VALU.
__device__ __forceinline__ void gate_ch(float iv, float ov, float uv, float fc,
                                        float& cv, float& h1)
{
  const float a  = __expf(-iv);
  const float b  = __expf(2.0f * uv);
  cv = (b - 1.0f) * __builtin_amdgcn_rcpf((1.0f + a) * (1.0f + b)) + fc;
  const float d  = __expf(-ov);
  const float e2 = __expf(2.0f * cv);
  h1 = (e2 - 1.0f) * __builtin_amdgcn_rcpf((1.0f + d) * (1.0f + e2));
}

// FC = sig(s0)*c0 + sig(s1)*c1 = (c0*(1+a1) + c1*(1+a0)) / ((1+a0)(1+a1))
__device__ __forceinline__ float gate_fc(float s0, float s1, float c0, float c1)
{
  const float a0 = __expf(-s0);
  const float a1 = __expf(-s1);
  return (c0 * (1.0f + a1) + c1 * (1.0f + a0)) *
         __builtin_amdgcn_rcpf((1.0f + a0) * (1.0f + a1));
}

// Converts INTERNAL X rows [0,65535) to bf16 (leaf rows consumed as f32 by
// leaf_gemm directly); packs weights. Wiou is packed to tile order:
// packed_row = (ch>>5)*96 + part*32 + (ch&31), so a tile's 96 B-rows are
// contiguous. Wf stays row-major (already tile-contiguous).
__global__ void prep_all(const float* __restrict__ X, bf16* __restrict__ Xb,
                         const float* __restrict__ Wioux, const float* __restrict__ Wiouh,
                         const float* __restrict__ Wfx, const float* __restrict__ Wfh,
                         const float* __restrict__ bioux, const float* __restrict__ biouh,
                         const float* __restrict__ bfx, const float* __restrict__ bfh,
                         bf16* __restrict__ Wiou, bf16* __restrict__ Wf,
                         float* __restrict__ biou, float* __restrict__ bfc)
{
  const int i = blockIdx.x * 256 + threadIdx.x;    // float4 index
  if (i < (65535 * 256) / 4) {
    const float4 v = ((const float4*)X)[i];
    union { ushort4 u; bf16 b[4]; } cv;
    cv.b[0] = (bf16)v.x; cv.b[1] = (bf16)v.y; cv.b[2] = (bf16)v.z; cv.b[3] = (bf16)v.w;
    ((ushort4*)Xb)[i] = cv.u;
  }
  const int el = i;                                 // 0 .. 524287 do weights
  if (el < 524288) {
    if (el < 768 * 512) {
      const int r = el >> 9, c = el & 511;
      const float v = (c < 256) ? Wioux[r * 256 + c] : Wiouh[r * 256 + c - 256];
      const int p = r >> 8, ch = r & 255;
      const int dst = (ch >> 5) * 96 + p * 32 + (ch & 31);
      Wiou[dst * 512 + c] = (bf16)v;
    } else {
      const int e2 = el - 768 * 512;
      const int r = e2 >> 9, c = e2 & 511;
      const float v = (c < 256) ? Wfx[r * 256 + c] : Wfh[r * 256 + c - 256];
      Wf[e2] = (bf16)v;
    }
    if (el < 768)       biou[el] = bioux[el] + biouh[el];
    else if (el < 1024) bfc[el - 768] = bfx[el - 768] + bfh[el - 768];
  }
}

// IOU tile: A[M x K] = [ Xb[xbase+row] | Hsin[row] ], B = packed Wiou.
// Tile: 128 rows x 32 channels (96 cols: part*32+ch). Each wave: 64 rows
// (waveM) x 16 channels (waveN) x 3 parts -> lane-local i,o,u.
// Epilogue: c = sig(i)tanh(u) + FC; h = sig(o)tanh(c); emit C, H, Hsum.
__device__ __forceinline__ void iou_tile(
    bf16* __restrict__ As /*128*64*/, bf16* __restrict__ Bs /*96*64*/,
    const bf16* __restrict__ Xb, int xbase,
    const bf16* __restrict__ Hsin, const bf16* __restrict__ FCb,
    const float* __restrict__ biou, const bf16* __restrict__ Wiou,
    bf16* __restrict__ Cst, bf16* __restrict__ H, bf16* __restrict__ Hsout,
    float* __restrict__ out, int M, int K, int isRoot, int bx, int by)
{
  const int t = threadIdx.x;
  const int wave = t >> 6, lane = t & 63;
  const int quad = lane >> 4, lc = lane & 15;
  const int waveM = wave >> 1, waveN = wave & 1;
  const int mBase = by * 128;
  const int chBase = bx * 32;
  const int lrow = lane >> 3;                      // 0..7
  const int lcol8 = ((lane & 7) ^ lrow) << 3;      // swizzled 8-elem block
  const int Mm1 = M - 1;
  f32x4 acc[4][3] = {};

  auto ktile = [&](const bf16* __restrict__ abase, int ka, int kb) {
#pragma unroll
    for (int ii = 0; ii < 4; ++ii) {
      const int idx = wave * 4 + ii;
      const int r = idx * 8 + lrow;
      int g = mBase + r; g = g > Mm1 ? Mm1 : g;
      GLD16(abase + (size_t)g * 256 + ka + lcol8, &As[idx * 512]);
    }
#pragma unroll
    for (int ii = 0; ii < 3; ++ii) {
      const int idx = wave * 3 + ii;
      const int rb = idx * 8 + lrow;               // 0..95, packed-contiguous
      GLD16(Wiou + ((size_t)(bx * 96 + rb)) * 512 + kb + lcol8, &Bs[idx * 512]);
    }
    __syncthreads();
#pragma unroll
    for (int kk = 0; kk < 64; kk += 32) {
      const int lb = (kk >> 3) + quad;
      bf16x8 a[4];
#pragma unroll
      for (int mf = 0; mf < 4; ++mf) {
        const int rA = waveM * 64 + mf * 16 + lc;
        a[mf] = *(const bf16x8*)&As[rA * 64 + ((lb ^ (rA & 7)) << 3)];
      }
#pragma unroll
      for (int p = 0; p < 3; ++p) {
        const int rB = p * 32 + waveN * 16 + lc;
        bf16x8 b = *(const bf16x8*)&Bs[rB * 64 + ((lb ^ (rB & 7)) << 3)];
#pragma unroll
        for (int mf = 0; mf < 4; ++mf)
          acc[mf][p] = __builtin_amdgcn_mfma_f32_16x16x32_bf16(a[mf], b, acc[mf][p], 0, 0, 0);
      }
    }
    __syncthreads();
  };

#pragma unroll
  for (int kt = 0; kt < 256; kt += 64) ktile(Xb + (size_t)xbase * 256, kt, kt);
  if (K == 512) {
#pragma unroll
    for (int kt = 0; kt < 256; kt += 64) ktile(Hsin, kt, kt + 256);
  }

  const int ch = chBase + waveN * 16 + lc;
  const float bi = biou[ch], bo = biou[256 + ch], bu = biou[512 + ch];
#pragma unroll
  for (int mf = 0; mf < 4; ++mf) {
    const int row0 = mBase + waveM * 64 + mf * 16 + quad * 4;
    float hv[4] = {0.f, 0.f, 0.f, 0.f};
#pragma unroll
    for (int r = 0; r < 4; ++r) {
      const int rw = row0 + r;
      if (rw < M) {
        const float fc = FCb ? (float)FCb[(size_t)rw * 256 + ch] : 0.0f;
        float cv, h1;
        gate_ch(acc[mf][0][r] + bi, acc[mf][1][r] + bo, acc[mf][2][r] + bu, fc, cv, h1);
        hv[r] = h1;
        Cst[(size_t)rw * 256 + ch] = (bf16)cv;
        H[(size_t)rw * 256 + ch] = (bf16)h1;
        if (isRoot && rw == 0) { out[ch] = cv; out[256 + ch] = h1; }
      }
    }
    if (row0 + 1 < M) Hsout[(size_t)(row0 >> 1) * 256 + ch] = (bf16)(hv[0] + hv[1]);
    if (row0 + 3 < M) Hsout[(size_t)((row0 >> 1) + 1) * 256 + ch] = (bf16)(hv[2] + hv[3]);
  }
}

// F tile over children: A[j] = [ Xb[parent(j)] | H[j] ], B = Wf (256 x 512).
// m97 profile: 128 x 128 tile, waves 2x2, acc 64. Used for level 15 only.
__device__ __forceinline__ void f_tile(
    bf16* __restrict__ As /*128*64*/, bf16* __restrict__ Bs /*128*64*/,
    const bf16* __restrict__ Xb, int xbase,
    const bf16* __restrict__ H, const bf16* __restrict__ Cc,
    const float* __restrict__ bfc, const bf16* __restrict__ Wf,
    bf16* __restrict__ FCb, int M2, int bx, int by)
{
  const int t = threadIdx.x;
  const int wave = t >> 6, lane = t & 63;
  const int quad = lane >> 4, lc = lane & 15;
  const int waveM = wave >> 1, waveN = wave & 1;
  const int mBase = by * 128;
  const int nBase = bx * 128;
  const int lrow = lane >> 3;
  const int lcol8 = ((lane & 7) ^ lrow) << 3;
  const int Mm1 = M2 - 1;
  f32x4 acc[4][4] = {};

  auto ktile = [&](bool xphase, int ka, int kb) {
#pragma unroll
    for (int ii = 0; ii < 4; ++ii) {
      const int idx = wave * 4 + ii;
      const int r = idx * 8 + lrow;
      int j = mBase + r; j = j > Mm1 ? Mm1 : j;
      const bf16* src = xphase ? Xb + (size_t)(xbase + (j >> 1)) * 256 + ka + lcol8
                               : H + (size_t)j * 256 + ka + lcol8;
      GLD16(src, &As[idx * 512]);
    }
#pragma unroll
    for (int ii = 0; ii < 4; ++ii) {
      const int idx = wave * 4 + ii;
      const int rb = idx * 8 + lrow;
      GLD16(Wf + (size_t)(nBase + rb) * 512 + kb + lcol8, &Bs[idx * 512]);
    }
    __syncthreads();
#pragma unroll
    for (int kk = 0; kk < 64; kk += 32) {
      const int lb = (kk >> 3) + quad;
      bf16x8 a[4];
#pragma unroll
      for (int mf = 0; mf < 4; ++mf) {
        const int rA = waveM * 64 + mf * 16 + lc;
        a[mf] = *(const bf16x8*)&As[rA * 64 + ((lb ^ (rA & 7)) << 3)];
      }
#pragma unroll
      for (int nf = 0; nf < 4; ++nf) {
        const int rB = waveN * 64 + nf * 16 + lc;
        bf16x8 b = *(const bf16x8*)&Bs[rB * 64 + ((lb ^ (rB & 7)) << 3)];
#pragma unroll
        for (int mf = 0; mf < 4; ++mf)
          acc[mf][nf] = __builtin_amdgcn_mfma_f32_16x16x32_bf16(a[mf], b, acc[mf][nf], 0, 0, 0);
      }
    }
    __syncthreads();
  };

#pragma unroll
  for (int kt = 0; kt < 256; kt += 64) ktile(true, kt, kt);
#pragma unroll
  for (int kt = 0; kt < 256; kt += 64) ktile(false, kt, kt + 256);

#pragma unroll
  for (int nf = 0; nf < 4; ++nf) {
    const int col = nBase + waveN * 64 + nf * 16 + lc;
    const float bv = bfc[col];
#pragma unroll
    for (int mf = 0; mf < 4; ++mf) {
      const int j0 = mBase + waveM * 64 + mf * 16 + quad * 4;
#pragma unroll
      for (int p = 0; p < 4; p += 2) {
        const int j = j0 + p;
        if (j < M2) {
          const float c0 = (float)Cc[(size_t)j * 256 + col];
          const float c1 = (float)Cc[(size_t)(j + 1) * 256 + col];
          FCb[(size_t)(j >> 1) * 256 + col] =
              (bf16)gate_fc(acc[mf][nf][p] + bv, acc[mf][nf][p + 1] + bv, c0, c1);
        }
      }
    }
  }
}

// Leaf GEMM: A rows read DIRECTLY from f32 X (reg-staged: float4 x2 -> cvt ->
// ds_write_b128 at the exact lane slot GLD16 would fill -> MFMA reads
// unchanged). K=256, no FC, M=65536 exactly (no clamps).
__global__ __launch_bounds__(256) void leaf_gemm(
    const float* __restrict__ X,
    const float* __restrict__ biou, const bf16* __restrict__ Wiou,
    bf16* __restrict__ Cst, bf16* __restrict__ H, bf16* __restrict__ Hsout)
{
  __shared__ bf16 As[128 * 64];   // 16 KB
  __shared__ bf16 Bs[96 * 64];    // 12 KB
  const int chunk = gridDim.x >> 3;
  const int tile = (blockIdx.x & 7) * chunk + (blockIdx.x >> 3);
  const int bx = tile & 7, by = tile >> 3;
  const int t = threadIdx.x;
  const int wave = t >> 6, lane = t & 63;
  const int quad = lane >> 4, lc = lane & 15;
  const int waveM = wave >> 1, waveN = wave & 1;
  const int mBase = by * 128;
  const int chBase = bx * 32;
  const int lrow = lane >> 3;
  const int lcol8 = ((lane & 7) ^ lrow) << 3;
  f32x4 acc[4][3] = {};

#pragma unroll
  for (int kt = 0; kt < 256; kt += 64) {
#pragma unroll
    for (int ii = 0; ii < 4; ++ii) {
      const int idx = wave * 4 + ii;
      const int g = mBase + idx * 8 + lrow;          // < 65536 always
      const float* sf = X + (size_t)(LEAF_START + g) * 256 + kt + lcol8;
      const float4 a0 = *(const float4*)sf;
      const float4 a1 = *(const float4*)(sf + 4);
      union { bf16x8 v; bf16 b[8]; } pk;
      pk.b[0] = (bf16)a0.x; pk.b[1] = (bf16)a0.y; pk.b[2] = (bf16)a0.z; pk.b[3] = (bf16)a0.w;
      pk.b[4] = (bf16)a1.x; pk.b[5] = (bf16)a1.y; pk.b[6] = (bf16)a1.z; pk.b[7] = (bf16)a1.w;
      *(bf16x8*)&As[idx * 512 + lane * 8] = pk.v;
    }
#pragma unroll
    for (int ii = 0; ii < 3; ++ii) {
      const int idx = wave * 3 + ii;
      const int rb = idx * 8 + lrow;
      GLD16(Wiou + ((size_t)(bx * 96 + rb)) * 512 + kt + lcol8, &Bs[idx * 512]);
    }
    __syncthreads();
#pragma unroll
    for (int kk = 0; kk < 64; kk += 32) {
      const int lb = (kk >> 3) + quad;
      bf16x8 a[4];
#pragma unroll
      for (int mf = 0; mf < 4; ++mf) {
        const int rA = waveM * 64 + mf * 16 + lc;
        a[mf] = *(const bf16x8*)&As[rA * 64 + ((lb ^ (rA & 7)) << 3)];
      }
#pragma unroll
      for (int p = 0; p < 3; ++p) {
        const int rB = p * 32 + waveN * 16 + lc;
        bf16x8 b = *(const bf16x8*)&Bs[rB * 64 + ((lb ^ (rB & 7)) << 3)];
#pragma unroll
        for (int mf = 0; mf < 4; ++mf)
          acc[mf][p] = __builtin_amdgcn_mfma_f32_16x16x32_bf16(a[mf], b, acc[mf][p], 0, 0, 0);
      }
    }
    __syncthreads();
  }

  const int ch = chBase + waveN * 16 + lc;
  const float bi = biou[ch], bo = biou[256 + ch], bu = biou[512 + ch];
#pragma unroll
  for (int mf = 0; mf < 4; ++mf) {
    const int row0 = mBase + waveM * 64 + mf * 16 + quad * 4;
    float hv[4];
#pragma unroll
    for (int r = 0; r < 4; ++r) {
      const int rw = row0 + r;
      float cv, h1;
      gate_ch(acc[mf][0][r] + bi, acc[mf][1][r] + bo, acc[mf][2][r] + bu, 0.0f, cv, h1);
      hv[r] = h1;
      Cst[(size_t)rw * 256 + ch] = (bf16)cv;
      H[(size_t)rw * 256 + ch] = (bf16)h1;
    }
    Hsout[(size_t)(row0 >> 1) * 256 + ch] = (bf16)(hv[0] + hv[1]);
    Hsout[(size_t)((row0 >> 1) + 1) * 256 + ch] = (bf16)(hv[2] + hv[3]);
  }
}

// Standalone wrappers for level 15. 1-D grid + XCD chunk swizzle.
__global__ __launch_bounds__(256) void iou_gemm(
    const bf16* __restrict__ Xb, int xbase,
    const bf16* __restrict__ Hsin, const bf16* __restrict__ FCb,
    const float* __restrict__ biou, const bf16* __restrict__ Wiou,
    bf16* __restrict__ Cst, bf16* __restrict__ H, bf16* __restrict__ Hsout,
    float* __restrict__ out, int M, int K, int isRoot)
{
  __shared__ bf16 As[128 * 64];   // 16 KB
  __shared__ bf16 Bs[96 * 64];    // 12 KB
  const int chunk = gridDim.x >> 3;                    // grid multiple of 8
  const int tile = (blockIdx.x & 7) * chunk + (blockIdx.x >> 3);
  iou_tile(As, Bs, Xb, xbase, Hsin, FCb, biou, Wiou, Cst, H, Hsout,
           out, M, K, isRoot, tile & 7, tile >> 3);
}

__global__ __launch_bounds__(256) void f_gemm(
    const bf16* __restrict__ Xb, int xbase,
    const bf16* __restrict__ H, const bf16* __restrict__ Cc,
    const float* __restrict__ bfc, const bf16* __restrict__ Wf,
    bf16* __restrict__ FCb, int M2)
{
  __shared__ bf16 As[128 * 64];
  __shared__ bf16 Bs[128 * 64];
  const int chunk = gridDim.x >> 3;                    // grid multiple of 8
  const int tile = (blockIdx.x & 7) * chunk + (blockIdx.x >> 3);
  f_tile(As, Bs, Xb, xbase, H, Cc, bfc, Wf, FCb, M2, tile & 1, tile >> 1);
}

// Fused per-level kernel (levels FUSE_TOP..0), INTERLEAVED F+IOU (r9/r10).
// 1-D grid with XCD chunk swizzle (bx fastest within a chunk) -> each XCD's
// 8 ch-blocks share a contiguous child-row slice (L2-resident), so the F
// phase's 8x A-replication stays on-die.
__global__ __launch_bounds__(256) void fused_level(
    const bf16* __restrict__ Xb, int xbase,
    const bf16* __restrict__ Hin, const bf16* __restrict__ Cin,
    const bf16* __restrict__ Hsin,
    const float* __restrict__ biou, const float* __restrict__ bfc,
    const bf16* __restrict__ Wiou, const bf16* __restrict__ Wf,
    bf16* __restrict__ Hout, bf16* __restrict__ Cout, bf16* __restrict__ Hsout,
    float* __restrict__ out, int count, int isRoot)
{
  __shared__ bf16 As_f[256 * 64];   // 32 KB
  __shared__ bf16 Bs_f[32 * 64];    //  4 KB
  __shared__ bf16 As_i[128 * 64];   // 16 KB
  __shared__ bf16 Bs_i[96 * 64];    // 12 KB
  __shared__ float FCs[128 * 32];   // 16 KB   total 80 KB

  const int t = threadIdx.x;
  const int wave = t >> 6, lane = t & 63;
  const int quad = lane >> 4, lc = lane & 15;
  const int waveM = wave >> 1, waveN = wave & 1;
  const int chunk = gridDim.x >> 3;                    // grid multiple of 8
  const int tile = (blockIdx.x & 7) * chunk + (blockIdx.x >> 3);
  const int bx = tile & 7, by = tile >> 3;
  const int mBase = by * 128;
  const int chBase = bx * 32;
  const int lrow = lane >> 3;
  const int lcol8 = ((lane & 7) ^ lrow) << 3;

  const int M = count, Mm1 = M - 1;
  const int M2 = count * 2, M2m1 = M2 - 1;

  f32x4 accf[4][2] = {};   // F: 64 child rows/wave x 32 cols
  f32x4 acci[4][3] = {};   // IOU: 64 rows (waveM) x 16 ch (waveN) x 3 parts

  // 8 combined stages; stage kt covers K-slice [kt*64, kt*64+64) of 512.
  // kt<4: x-part (A from Xb); kt>=4: h-part (A from Hin / Hsin).
#pragma unroll
  for (int kt = 0; kt < 8; ++kt) {
    const bool xph = kt < 4;
    const int ka = (kt & 3) * 64;        // source-row K offset
    const int kb = kt * 64;              // weight-row K offset (0..448)
    // F A: 32 issues (8/wave), 256 child rows
#pragma unroll
    for (int ii = 0; ii < 8; ++ii) {
      const int idx = wave * 8 + ii;
      const int rl = idx * 8 + lrow;
      int j = 2 * mBase + rl; j = j > M2m1 ? M2m1 : j;
      const bf16* src = xph ? Xb + (size_t)(xbase + (j >> 1)) * 256 + ka + lcol8
                            : Hin + (size_t)j * 256 + ka + lcol8;
      GLD16(src, &As_f[idx * 512]);
    }
    // F B: 4 issues (1/wave), 32 Wf rows
    {
      const int rb = wave * 8 + lrow;
      GLD16(Wf + (size_t)(chBase + rb) * 512 + kb + lcol8, &Bs_f[wave * 512]);
    }
    // IOU A: 16 issues (4/wave), 128 node rows
#pragma unroll
    for (int ii = 0; ii < 4; ++ii) {
      const int idx = wave * 4 + ii;
      const int r = idx * 8 + lrow;
      int g = mBase + r; g = g > Mm1 ? Mm1 : g;
      const bf16* src = xph ? Xb + (size_t)(xbase + g) * 256 + ka + lcol8
                            : Hsin + (size_t)g * 256 + ka + lcol8;
      GLD16(src, &As_i[idx * 512]);
    }
    // IOU B: 12 issues (3/wave), 96 packed Wiou rows
#pragma unroll
    for (int ii = 0; ii < 3; ++ii) {
      const int idx = wave * 3 + ii;
      const int rb = idx * 8 + lrow;               // 0..95
      GLD16(Wiou + ((size_t)(bx * 96 + rb)) * 512 + kb + lcol8, &Bs_i[idx * 512]);
    }
    __syncthreads();
#pragma unroll
    for (int kk = 0; kk < 64; kk += 32) {
      const int lb = (kk >> 3) + quad;
      // F MFMAs (16 per stage-half)
      bf16x8 af[4];
#pragma unroll
      for (int mf = 0; mf < 4; ++mf) {
        const int rA = wave * 64 + mf * 16 + lc;
        af[mf] = *(const bf16x8*)&As_f[rA * 64 + ((lb ^ (rA & 7)) << 3)];
      }
#pragma unroll
      for (int nf = 0; nf < 2; ++nf) {
        const int rB = nf * 16 + lc;
        bf16x8 b = *(const bf16x8*)&Bs_f[rB * 64 + ((lb ^ (rB & 7)) << 3)];
#pragma unroll
        for (int mf = 0; mf < 4; ++mf)
          accf[mf][nf] = __builtin_amdgcn_mfma_f32_16x16x32_bf16(af[mf], b, accf[mf][nf], 0, 0, 0);
      }
      // IOU MFMAs (24 per stage-half)
      bf16x8 ai[4];
#pragma unroll
      for (int mf = 0; mf < 4; ++mf) {
        const int rA = waveM * 64 + mf * 16 + lc;
        ai[mf] = *(const bf16x8*)&As_i[rA * 64 + ((lb ^ (rA & 7)) << 3)];
      }
#pragma unroll
      for (int p = 0; p < 3; ++p) {
        const int rB = p * 32 + waveN * 16 + lc;
        bf16x8 b = *(const bf16x8*)&Bs_i[rB * 64 + ((lb ^ (rB & 7)) << 3)];
#pragma unroll
        for (int mf = 0; mf < 4; ++mf)
          acci[mf][p] = __builtin_amdgcn_mfma_f32_16x16x32_bf16(ai[mf], b, acci[mf][p], 0, 0, 0);
      }
    }
    __syncthreads();
  }

  // F epilogue: FC pairs -> LDS (f32, rows rl>>1 in [0,128), cols 0..31)
#pragma unroll
  for (int nf = 0; nf < 2; ++nf) {
    const int ci = nf * 16 + lc;
    const float bv = bfc[chBase + ci];
#pragma unroll
    for (int mf = 0; mf < 4; ++mf) {
      const int rl0 = wave * 64 + mf * 16 + quad * 4;
#pragma unroll
      for (int p = 0; p < 4; p += 2) {
        const int rl = rl0 + p;                    // even
        const int j = 2 * mBase + rl;
        if (j + 1 < M2) {
          const float c0 = (float)Cin[(size_t)j * 256 + chBase + ci];
          const float c1 = (float)Cin[(size_t)(j + 1) * 256 + chBase + ci];
          FCs[(rl >> 1) * 32 + ci] =
              gate_fc(accf[mf][nf][p] + bv, accf[mf][nf][p + 1] + bv, c0, c1);
        }
      }
    }
  }
  __syncthreads();   // FCs visible to all waves

  // IOU epilogue (FC from LDS)
  const int ch = chBase + waveN * 16 + lc;
  const float bi = biou[ch], bo = biou[256 + ch], bu = biou[512 + ch];
#pragma unroll
  for (int mf = 0; mf < 4; ++mf) {
    const int row0 = mBase + waveM * 64 + mf * 16 + quad * 4;
    float hv[4] = {0.f, 0.f, 0.f, 0.f};
#pragma unroll
    for (int r = 0; r < 4; ++r) {
      const int rw = row0 + r;
      if (rw < M) {
        const float fc = FCs[(rw - mBase) * 32 + (ch - chBase)];
        float cv, h1;
        gate_ch(acci[mf][0][r] + bi, acci[mf][1][r] + bo, acci[mf][2][r] + bu, fc, cv, h1);
        hv[r] = h1;
        Cout[(size_t)rw * 256 + ch] = (bf16)cv;
        Hout[(size_t)rw * 256 + ch] = (bf16)h1;
        if (isRoot && rw == 0) { out[ch] = cv; out[256 + ch] = h1; }
      }
    }
    if (row0 + 1 < M) Hsout[(size_t)(row0 >> 1) * 256 + ch] = (bf16)(hv[0] + hv[1]);
    if (row0 + 3 < M) Hsout[(size_t)((row0 >> 1) + 1) * 256 + ch] = (bf16)(hv[2] + hv[3]);
  }
}

extern "C" void kernel_launch(void* const* d_in, const int* in_sizes, int n_in,
                              void* d_out, int out_size, void* d_ws, size_t ws_size,
                              hipStream_t stream)
{
  const float* X      = (const float*)d_in[0];
  const float* Wioux  = (const float*)d_in[1];
  const float* bioux  = (const float*)d_in[2];
  const float* Wiouh  = (const float*)d_in[3];
  const float* biouh  = (const float*)d_in[4];
  const float* Wfx    = (const float*)d_in[5];
  const float* bfx    = (const float*)d_in[6];
  const float* Wfh    = (const float*)d_in[7];
  const float* bfh    = (const float*)d_in[8];
  float* out = (float*)d_out;
  (void)in_sizes; (void)n_in; (void)out_size; (void)ws_size;

  // workspace: ~172 MB
  char* ws = (char*)d_ws;
  size_t off = 0;
  auto alloc = [&](size_t bytes) -> char* {
    char* p = ws + off;
    off += (bytes + 255) & ~(size_t)255;
    return p;
  };
  bf16*  Wiou = (bf16*)alloc((size_t)768 * 512 * 2);     // packed tile order
  bf16*  Wf   = (bf16*)alloc((size_t)256 * 512 * 2);
  float* biou = (float*)alloc(768 * 4);
  float* bfc  = (float*)alloc(256 * 4);
  bf16*  Xb   = (bf16*)alloc((size_t)65536 * 256 * 2);   // 33.6 MB (internal rows only)
  bf16*  H    = (bf16*)alloc((size_t)65536 * 256 * 2);   // 33.6 MB (level-local)
  bf16*  HsA  = (bf16*)alloc((size_t)32768 * 256 * 2);   // 16.8 MB
  bf16*  HsB  = (bf16*)alloc((size_t)32768 * 256 * 2);   // 16.8 MB
  bf16*  FCb  = (bf16*)alloc((size_t)32768 * 256 * 2);   // 16.8 MB (level 15)
  bf16*  C    = (bf16*)alloc((size_t)65536 * 256 * 2);   // 33.6 MB (level-local)
  bf16*  H2   = (bf16*)alloc((size_t)16384 * 256 * 2);   // 8.4 MB (fused ping-pong)
  bf16*  C2   = (bf16*)alloc((size_t)16384 * 256 * 2);   // 8.4 MB

  prep_all<<<16385, 256, 0, stream>>>(X, Xb, Wioux, Wiouh, Wfx, Wfh,
                                      bioux, biouh, bfx, bfh,
                                      Wiou, Wf, biou, bfc);

  // Leaf level: K=256, A from f32 X directly; writes C/H [0,65536), HsA.
  leaf_gemm<<<8 * 512, 256, 0, stream>>>(X, biou, Wiou, C, H, HsA);

  // Level 15 (two dispatches; 1-D swizzled grids).
  for (int lvl = 15; lvl > FUSE_TOP; --lvl) {
    const int count = 1 << lvl;
    const int s = count - 1;
    const int M2 = 2 * count;
    const bf16* Hsin = (lvl & 1) ? HsA : HsB;
    bf16* Hsout      = (lvl & 1) ? HsB : HsA;
    f_gemm<<<2 * (M2 / 128), 256, 0, stream>>>(
        Xb, s, H, C, bfc, Wf, FCb, M2);
    iou_gemm<<<8 * (count / 128), 256, 0, stream>>>(
        Xb, s, Hsin, FCb, biou, Wiou, C, H, Hsout, out, count, 512, 0);
  }

  // Fused levels 14..0: one dispatch per level; H/C ping-pong between the
  // big level-local buffers and the small H2/C2 pair.
  for (int lvl = FUSE_TOP; lvl >= 0; --lvl) {
    const int count = 1 << lvl;
    const int s = count - 1;
    const bf16* Hsin = (lvl & 1) ? HsA : HsB;
    bf16* Hsout      = (lvl & 1) ? HsB : HsA;
    const int pp = (FUSE_TOP - lvl) & 1;     // 0: in=H,C out=H2,C2 ; 1: reverse
    const bf16* Hin = pp ? H2 : H;
    const bf16* Cin = pp ? C2 : C;
    bf16* Hout      = pp ? H  : H2;
    bf16* Cout      = pp ? C  : C2;
    fused_level<<<8 * ((count + 127) / 128), 256, 0, stream>>>(
        Xb, s, Hin, Cin, Hsin, biou, bfc, Wiou, Wf,
        Hout, Cout, Hsout, out, count, lvl == 0);
  }
}

// Round 10
// 639.507 us; speedup vs baseline: 1.0244x; 1.0244x over previous
//
#include <hip/hip_runtime.h>
#include <hip/hip_bf16.h>
#include <cstdint>
#include <cstddef>

// ---------------------------------------------------------------------------
// ChildSumTreeLSTM, complete binary tree N=131071=2^17-1, dim 256.
// Round 14: leaf REVERTED to r12's GLD16-from-Xb path (r13 post-mortem:
// reg-staged f32 A exposed HBM latency serially: leaf 77->101 us, MfmaUtil
// 9.9%; prep saving -18 didn't cover it). prep_all converts ALL X rows again.
// Wiou tile-order packing kept (neutral-to-positive, simpler addresses).
// NEW: fused_level x-stages (kt<4) skip As_f staging entirely -- F's A rows
// (Xb[parent]) are EXACTLY the 128 rows already in As_i for IOU (level nodes
// == parents, same K slice). F MFMAs read As_i at row (child>>1) with the
// same XOR swizzle; lane pairs hit the same 16B -> LDS broadcast (free).
// Halves staging issues/bytes in 4 of 8 stages of every fused level.
//   fused LDS: 32+4+16+12+16 = 80 KB static; acc 80 VGPR (F 32 + IOU 48)
// ---------------------------------------------------------------------------

typedef __bf16 bf16;
typedef bf16 bf16x8 __attribute__((ext_vector_type(8)));
typedef float f32x4 __attribute__((ext_vector_type(4)));

#define LEAF_START 65535
#define LEAF_COUNT 65536
#define FUSE_TOP   14     // levels FUSE_TOP..0 use the fused one-dispatch-per-level kernel

// async global->LDS, 16 B per lane, dest = base + lane*16
#define GLD16(g, l) __builtin_amdgcn_global_load_lds(                         \
    (const __attribute__((address_space(1))) void*)(g),                       \
    (__attribute__((address_space(3))) void*)(l), 16, 0, 0)

// c = sig(i)*tanh(u) + fc ; h = sig(o)*tanh(c).  Merged: 6 trans + ~8 VALU.
__device__ __forceinline__ void gate_ch(float iv, float ov, float uv, float fc,
                                        float& cv, float& h1)
{
  const float a  = __expf(-iv);
  const float b  = __expf(2.0f * uv);
  cv = (b - 1.0f) * __builtin_amdgcn_rcpf((1.0f + a) * (1.0f + b)) + fc;
  const float d  = __expf(-ov);
  const float e2 = __expf(2.0f * cv);
  h1 = (e2 - 1.0f) * __builtin_amdgcn_rcpf((1.0f + d) * (1.0f + e2));
}

// FC = sig(s0)*c0 + sig(s1)*c1 = (c0*(1+a1) + c1*(1+a0)) / ((1+a0)(1+a1))
__device__ __forceinline__ float gate_fc(float s0, float s1, float c0, float c1)
{
  const float a0 = __expf(-s0);
  const float a1 = __expf(-s1);
  return (c0 * (1.0f + a1) + c1 * (1.0f + a0)) *
         __builtin_amdgcn_rcpf((1.0f + a0) * (1.0f + a1));
}

// Converts ALL X rows to bf16; packs weights. Wiou packed to tile order:
// packed_row = (ch>>5)*96 + part*32 + (ch&31) -> a tile's 96 B-rows are
// contiguous. Wf stays row-major (already tile-contiguous).
__global__ void prep_all(const float* __restrict__ X, bf16* __restrict__ Xb,
                         const float* __restrict__ Wioux, const float* __restrict__ Wiouh,
                         const float* __restrict__ Wfx, const float* __restrict__ Wfh,
                         const float* __restrict__ bioux, const float* __restrict__ biouh,
                         const float* __restrict__ bfx, const float* __restrict__ bfh,
                         bf16* __restrict__ Wiou, bf16* __restrict__ Wf,
                         float* __restrict__ biou, float* __restrict__ bfc)
{
  const int i = blockIdx.x * 256 + threadIdx.x;    // float4 index
  if (i < (131071 * 256) / 4) {
    const float4 v = ((const float4*)X)[i];
    union { ushort4 u; bf16 b[4]; } cv;
    cv.b[0] = (bf16)v.x; cv.b[1] = (bf16)v.y; cv.b[2] = (bf16)v.z; cv.b[3] = (bf16)v.w;
    ((ushort4*)Xb)[i] = cv.u;
  }
  const int el = i;                                 // 0 .. 524287 do weights
  if (el < 524288) {
    if (el < 768 * 512) {
      const int r = el >> 9, c = el & 511;
      const float v = (c < 256) ? Wioux[r * 256 + c] : Wiouh[r * 256 + c - 256];
      const int p = r >> 8, ch = r & 255;
      const int dst = (ch >> 5) * 96 + p * 32 + (ch & 31);
      Wiou[dst * 512 + c] = (bf16)v;
    } else {
      const int e2 = el - 768 * 512;
      const int r = e2 >> 9, c = e2 & 511;
      const float v = (c < 256) ? Wfx[r * 256 + c] : Wfh[r * 256 + c - 256];
      Wf[e2] = (bf16)v;
    }
    if (el < 768)       biou[el] = bioux[el] + biouh[el];
    else if (el < 1024) bfc[el - 768] = bfx[el - 768] + bfh[el - 768];
  }
}

// IOU tile: A[M x K] = [ Xb[xbase+row] | Hsin[row] ], B = packed Wiou.
// Tile: 128 rows x 32 channels (96 cols: part*32+ch). Each wave: 64 rows
// (waveM) x 16 channels (waveN) x 3 parts -> lane-local i,o,u.
// Epilogue: c = sig(i)tanh(u) + FC; h = sig(o)tanh(c); emit C, H, Hsum.
__device__ __forceinline__ void iou_tile(
    bf16* __restrict__ As /*128*64*/, bf16* __restrict__ Bs /*96*64*/,
    const bf16* __restrict__ Xb, int xbase,
    const bf16* __restrict__ Hsin, const bf16* __restrict__ FCb,
    const float* __restrict__ biou, const bf16* __restrict__ Wiou,
    bf16* __restrict__ Cst, bf16* __restrict__ H, bf16* __restrict__ Hsout,
    float* __restrict__ out, int M, int K, int isRoot, int bx, int by)
{
  const int t = threadIdx.x;
  const int wave = t >> 6, lane = t & 63;
  const int quad = lane >> 4, lc = lane & 15;
  const int waveM = wave >> 1, waveN = wave & 1;
  const int mBase = by * 128;
  const int chBase = bx * 32;
  const int lrow = lane >> 3;                      // 0..7
  const int lcol8 = ((lane & 7) ^ lrow) << 3;      // swizzled 8-elem block
  const int Mm1 = M - 1;
  f32x4 acc[4][3] = {};

  auto ktile = [&](const bf16* __restrict__ abase, int ka, int kb) {
#pragma unroll
    for (int ii = 0; ii < 4; ++ii) {
      const int idx = wave * 4 + ii;
      const int r = idx * 8 + lrow;
      int g = mBase + r; g = g > Mm1 ? Mm1 : g;
      GLD16(abase + (size_t)g * 256 + ka + lcol8, &As[idx * 512]);
    }
#pragma unroll
    for (int ii = 0; ii < 3; ++ii) {
      const int idx = wave * 3 + ii;
      const int rb = idx * 8 + lrow;               // 0..95, packed-contiguous
      GLD16(Wiou + ((size_t)(bx * 96 + rb)) * 512 + kb + lcol8, &Bs[idx * 512]);
    }
    __syncthreads();
#pragma unroll
    for (int kk = 0; kk < 64; kk += 32) {
      const int lb = (kk >> 3) + quad;
      bf16x8 a[4];
#pragma unroll
      for (int mf = 0; mf < 4; ++mf) {
        const int rA = waveM * 64 + mf * 16 + lc;
        a[mf] = *(const bf16x8*)&As[rA * 64 + ((lb ^ (rA & 7)) << 3)];
      }
#pragma unroll
      for (int p = 0; p < 3; ++p) {
        const int rB = p * 32 + waveN * 16 + lc;
        bf16x8 b = *(const bf16x8*)&Bs[rB * 64 + ((lb ^ (rB & 7)) << 3)];
#pragma unroll
        for (int mf = 0; mf < 4; ++mf)
          acc[mf][p] = __builtin_amdgcn_mfma_f32_16x16x32_bf16(a[mf], b, acc[mf][p], 0, 0, 0);
      }
    }
    __syncthreads();
  };

#pragma unroll
  for (int kt = 0; kt < 256; kt += 64) ktile(Xb + (size_t)xbase * 256, kt, kt);
  if (K == 512) {
#pragma unroll
    for (int kt = 0; kt < 256; kt += 64) ktile(Hsin, kt, kt + 256);
  }

  const int ch = chBase + waveN * 16 + lc;
  const float bi = biou[ch], bo = biou[256 + ch], bu = biou[512 + ch];
#pragma unroll
  for (int mf = 0; mf < 4; ++mf) {
    const int row0 = mBase + waveM * 64 + mf * 16 + quad * 4;
    float hv[4] = {0.f, 0.f, 0.f, 0.f};
#pragma unroll
    for (int r = 0; r < 4; ++r) {
      const int rw = row0 + r;
      if (rw < M) {
        const float fc = FCb ? (float)FCb[(size_t)rw * 256 + ch] : 0.0f;
        float cv, h1;
        gate_ch(acc[mf][0][r] + bi, acc[mf][1][r] + bo, acc[mf][2][r] + bu, fc, cv, h1);
        hv[r] = h1;
        Cst[(size_t)rw * 256 + ch] = (bf16)cv;
        H[(size_t)rw * 256 + ch] = (bf16)h1;
        if (isRoot && rw == 0) { out[ch] = cv; out[256 + ch] = h1; }
      }
    }
    if (row0 + 1 < M) Hsout[(size_t)(row0 >> 1) * 256 + ch] = (bf16)(hv[0] + hv[1]);
    if (row0 + 3 < M) Hsout[(size_t)((row0 >> 1) + 1) * 256 + ch] = (bf16)(hv[2] + hv[3]);
  }
}

// F tile over children: A[j] = [ Xb[parent(j)] | H[j] ], B = Wf (256 x 512).
// m97 profile: 128 x 128 tile, waves 2x2, acc 64. Used for level 15 only.
__device__ __forceinline__ void f_tile(
    bf16* __restrict__ As /*128*64*/, bf16* __restrict__ Bs /*128*64*/,
    const bf16* __restrict__ Xb, int xbase,
    const bf16* __restrict__ H, const bf16* __restrict__ Cc,
    const float* __restrict__ bfc, const bf16* __restrict__ Wf,
    bf16* __restrict__ FCb, int M2, int bx, int by)
{
  const int t = threadIdx.x;
  const int wave = t >> 6, lane = t & 63;
  const int quad = lane >> 4, lc = lane & 15;
  const int waveM = wave >> 1, waveN = wave & 1;
  const int mBase = by * 128;
  const int nBase = bx * 128;
  const int lrow = lane >> 3;
  const int lcol8 = ((lane & 7) ^ lrow) << 3;
  const int Mm1 = M2 - 1;
  f32x4 acc[4][4] = {};

  auto ktile = [&](bool xphase, int ka, int kb) {
#pragma unroll
    for (int ii = 0; ii < 4; ++ii) {
      const int idx = wave * 4 + ii;
      const int r = idx * 8 + lrow;
      int j = mBase + r; j = j > Mm1 ? Mm1 : j;
      const bf16* src = xphase ? Xb + (size_t)(xbase + (j >> 1)) * 256 + ka + lcol8
                               : H + (size_t)j * 256 + ka + lcol8;
      GLD16(src, &As[idx * 512]);
    }
#pragma unroll
    for (int ii = 0; ii < 4; ++ii) {
      const int idx = wave * 4 + ii;
      const int rb = idx * 8 + lrow;
      GLD16(Wf + (size_t)(nBase + rb) * 512 + kb + lcol8, &Bs[idx * 512]);
    }
    __syncthreads();
#pragma unroll
    for (int kk = 0; kk < 64; kk += 32) {
      const int lb = (kk >> 3) + quad;
      bf16x8 a[4];
#pragma unroll
      for (int mf = 0; mf < 4; ++mf) {
        const int rA = waveM * 64 + mf * 16 + lc;
        a[mf] = *(const bf16x8*)&As[rA * 64 + ((lb ^ (rA & 7)) << 3)];
      }
#pragma unroll
      for (int nf = 0; nf < 4; ++nf) {
        const int rB = waveN * 64 + nf * 16 + lc;
        bf16x8 b = *(const bf16x8*)&Bs[rB * 64 + ((lb ^ (rB & 7)) << 3)];
#pragma unroll
        for (int mf = 0; mf < 4; ++mf)
          acc[mf][nf] = __builtin_amdgcn_mfma_f32_16x16x32_bf16(a[mf], b, acc[mf][nf], 0, 0, 0);
      }
    }
    __syncthreads();
  };

#pragma unroll
  for (int kt = 0; kt < 256; kt += 64) ktile(true, kt, kt);
#pragma unroll
  for (int kt = 0; kt < 256; kt += 64) ktile(false, kt, kt + 256);

#pragma unroll
  for (int nf = 0; nf < 4; ++nf) {
    const int col = nBase + waveN * 64 + nf * 16 + lc;
    const float bv = bfc[col];
#pragma unroll
    for (int mf = 0; mf < 4; ++mf) {
      const int j0 = mBase + waveM * 64 + mf * 16 + quad * 4;
#pragma unroll
      for (int p = 0; p < 4; p += 2) {
        const int j = j0 + p;
        if (j < M2) {
          const float c0 = (float)Cc[(size_t)j * 256 + col];
          const float c1 = (float)Cc[(size_t)(j + 1) * 256 + col];
          FCb[(size_t)(j >> 1) * 256 + col] =
              (bf16)gate_fc(acc[mf][nf][p] + bv, acc[mf][nf][p + 1] + bv, c0, c1);
        }
      }
    }
  }
}

// Standalone wrappers for level 15 + leaf. 1-D grid + XCD chunk swizzle.
__global__ __launch_bounds__(256) void iou_gemm(
    const bf16* __restrict__ Xb, int xbase,
    const bf16* __restrict__ Hsin, const bf16* __restrict__ FCb,
    const float* __restrict__ biou, const bf16* __restrict__ Wiou,
    bf16* __restrict__ Cst, bf16* __restrict__ H, bf16* __restrict__ Hsout,
    float* __restrict__ out, int M, int K, int isRoot)
{
  __shared__ bf16 As[128 * 64];   // 16 KB
  __shared__ bf16 Bs[96 * 64];    // 12 KB
  const int chunk = gridDim.x >> 3;                    // grid multiple of 8
  const int tile = (blockIdx.x & 7) * chunk + (blockIdx.x >> 3);
  iou_tile(As, Bs, Xb, xbase, Hsin, FCb, biou, Wiou, Cst, H, Hsout,
           out, M, K, isRoot, tile & 7, tile >> 3);
}

__global__ __launch_bounds__(256) void f_gemm(
    const bf16* __restrict__ Xb, int xbase,
    const bf16* __restrict__ H, const bf16* __restrict__ Cc,
    const float* __restrict__ bfc, const bf16* __restrict__ Wf,
    bf16* __restrict__ FCb, int M2)
{
  __shared__ bf16 As[128 * 64];
  __shared__ bf16 Bs[128 * 64];
  const int chunk = gridDim.x >> 3;                    // grid multiple of 8
  const int tile = (blockIdx.x & 7) * chunk + (blockIdx.x >> 3);
  f_tile(As, Bs, Xb, xbase, H, Cc, bfc, Wf, FCb, M2, tile & 1, tile >> 1);
}

// Fused per-level kernel (levels FUSE_TOP..0), INTERLEAVED F+IOU.
// x-stages (kt<4): F's A rows (Xb[parent]) are EXACTLY As_i's rows (level
// nodes == parents, same K slice) -> no As_f staging; F MFMAs read As_i at
// row (child>>1), lane pairs broadcast-read the same 16B (free, m136).
// h-stages (kt>=4) stage As_f from Hin as before.
__global__ __launch_bounds__(256) void fused_level(
    const bf16* __restrict__ Xb, int xbase,
    const bf16* __restrict__ Hin, const bf16* __restrict__ Cin,
    const bf16* __restrict__ Hsin,
    const float* __restrict__ biou, const float* __restrict__ bfc,
    const bf16* __restrict__ Wiou, const bf16* __restrict__ Wf,
    bf16* __restrict__ Hout, bf16* __restrict__ Cout, bf16* __restrict__ Hsout,
    float* __restrict__ out, int count, int isRoot)
{
  __shared__ bf16 As_f[256 * 64];   // 32 KB (h-stages only)
  __shared__ bf16 Bs_f[32 * 64];    //  4 KB
  __shared__ bf16 As_i[128 * 64];   // 16 KB
  __shared__ bf16 Bs_i[96 * 64];    // 12 KB
  __shared__ float FCs[128 * 32];   // 16 KB   total 80 KB

  const int t = threadIdx.x;
  const int wave = t >> 6, lane = t & 63;
  const int quad = lane >> 4, lc = lane & 15;
  const int waveM = wave >> 1, waveN = wave & 1;
  const int chunk = gridDim.x >> 3;                    // grid multiple of 8
  const int tile = (blockIdx.x & 7) * chunk + (blockIdx.x >> 3);
  const int bx = tile & 7, by = tile >> 3;
  const int mBase = by * 128;
  const int chBase = bx * 32;
  const int lrow = lane >> 3;
  const int lcol8 = ((lane & 7) ^ lrow) << 3;

  const int M = count, Mm1 = M - 1;
  const int M2 = count * 2, M2m1 = M2 - 1;

  f32x4 accf[4][2] = {};   // F: 64 child rows/wave x 32 cols
  f32x4 acci[4][3] = {};   // IOU: 64 rows (waveM) x 16 ch (waveN) x 3 parts

  // 8 combined stages; stage kt covers K-slice [kt*64, kt*64+64) of 512.
  // kt<4: x-part (A from Xb; F shares As_i); kt>=4: h-part (Hin / Hsin).
#pragma unroll
  for (int kt = 0; kt < 8; ++kt) {
    const bool xph = kt < 4;
    const int ka = (kt & 3) * 64;        // source-row K offset
    const int kb = kt * 64;              // weight-row K offset (0..448)
    // F A: only for h-stages (32 issues, 8/wave, 256 child rows from Hin)
    if (!xph) {
#pragma unroll
      for (int ii = 0; ii < 8; ++ii) {
        const int idx = wave * 8 + ii;
        const int rl = idx * 8 + lrow;
        int j = 2 * mBase + rl; j = j > M2m1 ? M2m1 : j;
        GLD16(Hin + (size_t)j * 256 + ka + lcol8, &As_f[idx * 512]);
      }
    }
    // F B: 4 issues (1/wave), 32 Wf rows
    {
      const int rb = wave * 8 + lrow;
      GLD16(Wf + (size_t)(chBase + rb) * 512 + kb + lcol8, &Bs_f[wave * 512]);
    }
    // IOU A: 16 issues (4/wave), 128 node rows
#pragma unroll
    for (int ii = 0; ii < 4; ++ii) {
      const int idx = wave * 4 + ii;
      const int r = idx * 8 + lrow;
      int g = mBase + r; g = g > Mm1 ? Mm1 : g;
      const bf16* src = xph ? Xb + (size_t)(xbase + g) * 256 + ka + lcol8
                            : Hsin + (size_t)g * 256 + ka + lcol8;
      GLD16(src, &As_i[idx * 512]);
    }
    // IOU B: 12 issues (3/wave), 96 packed Wiou rows
#pragma unroll
    for (int ii = 0; ii < 3; ++ii) {
      const int idx = wave * 3 + ii;
      const int rb = idx * 8 + lrow;               // 0..95
      GLD16(Wiou + ((size_t)(bx * 96 + rb)) * 512 + kb + lcol8, &Bs_i[idx * 512]);
    }
    __syncthreads();
#pragma unroll
    for (int kk = 0; kk < 64; kk += 32) {
      const int lb = (kk >> 3) + quad;
      // F MFMAs (16 per stage-half); x-stages read parent rows from As_i
      bf16x8 af[4];
#pragma unroll
      for (int mf = 0; mf < 4; ++mf) {
        const int rAc = wave * 64 + mf * 16 + lc;      // child-local row
        if (xph) {
          const int pr = rAc >> 1;                     // parent-local row
          af[mf] = *(const bf16x8*)&As_i[pr * 64 + ((lb ^ (pr & 7)) << 3)];
        } else {
          af[mf] = *(const bf16x8*)&As_f[rAc * 64 + ((lb ^ (rAc & 7)) << 3)];
        }
      }
#pragma unroll
      for (int nf = 0; nf < 2; ++nf) {
        const int rB = nf * 16 + lc;
        bf16x8 b = *(const bf16x8*)&Bs_f[rB * 64 + ((lb ^ (rB & 7)) << 3)];
#pragma unroll
        for (int mf = 0; mf < 4; ++mf)
          accf[mf][nf] = __builtin_amdgcn_mfma_f32_16x16x32_bf16(af[mf], b, accf[mf][nf], 0, 0, 0);
      }
      // IOU MFMAs (24 per stage-half)
      bf16x8 ai[4];
#pragma unroll
      for (int mf = 0; mf < 4; ++mf) {
        const int rA = waveM * 64 + mf * 16 + lc;
        ai[mf] = *(const bf16x8*)&As_i[rA * 64 + ((lb ^ (rA & 7)) << 3)];
      }
#pragma unroll
      for (int p = 0; p < 3; ++p) {
        const int rB = p * 32 + waveN * 16 + lc;
        bf16x8 b = *(const bf16x8*)&Bs_i[rB * 64 + ((lb ^ (rB & 7)) << 3)];
#pragma unroll
        for (int mf = 0; mf < 4; ++mf)
          acci[mf][p] = __builtin_amdgcn_mfma_f32_16x16x32_bf16(ai[mf], b, acci[mf][p], 0, 0, 0);
      }
    }
    __syncthreads();
  }

  // F epilogue: FC pairs -> LDS (f32, rows rl>>1 in [0,128), cols 0..31)
#pragma unroll
  for (int nf = 0; nf < 2; ++nf) {
    const int ci = nf * 16 + lc;
    const float bv = bfc[chBase + ci];
#pragma unroll
    for (int mf = 0; mf < 4; ++mf) {
      const int rl0 = wave * 64 + mf * 16 + quad * 4;
#pragma unroll
      for (int p = 0; p < 4; p += 2) {
        const int rl = rl0 + p;                    // even
        const int j = 2 * mBase + rl;
        if (j + 1 < M2) {
          const float c0 = (float)Cin[(size_t)j * 256 + chBase + ci];
          const float c1 = (float)Cin[(size_t)(j + 1) * 256 + chBase + ci];
          FCs[(rl >> 1) * 32 + ci] =
              gate_fc(accf[mf][nf][p] + bv, accf[mf][nf][p + 1] + bv, c0, c1);
        }
      }
    }
  }
  __syncthreads();   // FCs visible to all waves

  // IOU epilogue (FC from LDS)
  const int ch = chBase + waveN * 16 + lc;
  const float bi = biou[ch], bo = biou[256 + ch], bu = biou[512 + ch];
#pragma unroll
  for (int mf = 0; mf < 4; ++mf) {
    const int row0 = mBase + waveM * 64 + mf * 16 + quad * 4;
    float hv[4] = {0.f, 0.f, 0.f, 0.f};
#pragma unroll
    for (int r = 0; r < 4; ++r) {
      const int rw = row0 + r;
      if (rw < M) {
        const float fc = FCs[(rw - mBase) * 32 + (ch - chBase)];
        float cv, h1;
        gate_ch(acci[mf][0][r] + bi, acci[mf][1][r] + bo, acci[mf][2][r] + bu, fc, cv, h1);
        hv[r] = h1;
        Cout[(size_t)rw * 256 + ch] = (bf16)cv;
        Hout[(size_t)rw * 256 + ch] = (bf16)h1;
        if (isRoot && rw == 0) { out[ch] = cv; out[256 + ch] = h1; }
      }
    }
    if (row0 + 1 < M) Hsout[(size_t)(row0 >> 1) * 256 + ch] = (bf16)(hv[0] + hv[1]);
    if (row0 + 3 < M) Hsout[(size_t)((row0 >> 1) + 1) * 256 + ch] = (bf16)(hv[2] + hv[3]);
  }
}

extern "C" void kernel_launch(void* const* d_in, const int* in_sizes, int n_in,
                              void* d_out, int out_size, void* d_ws, size_t ws_size,
                              hipStream_t stream)
{
  const float* X      = (const float*)d_in[0];
  const float* Wioux  = (const float*)d_in[1];
  const float* bioux  = (const float*)d_in[2];
  const float* Wiouh  = (const float*)d_in[3];
  const float* biouh  = (const float*)d_in[4];
  const float* Wfx    = (const float*)d_in[5];
  const float* bfx    = (const float*)d_in[6];
  const float* Wfh    = (const float*)d_in[7];
  const float* bfh    = (const float*)d_in[8];
  float* out = (float*)d_out;
  (void)in_sizes; (void)n_in; (void)out_size; (void)ws_size;

  // workspace: ~205 MB
  char* ws = (char*)d_ws;
  size_t off = 0;
  auto alloc = [&](size_t bytes) -> char* {
    char* p = ws + off;
    off += (bytes + 255) & ~(size_t)255;
    return p;
  };
  bf16*  Wiou = (bf16*)alloc((size_t)768 * 512 * 2);     // packed tile order
  bf16*  Wf   = (bf16*)alloc((size_t)256 * 512 * 2);
  float* biou = (float*)alloc(768 * 4);
  float* bfc  = (float*)alloc(256 * 4);
  bf16*  Xb   = (bf16*)alloc((size_t)131071 * 256 * 2);  // 67.1 MB
  bf16*  H    = (bf16*)alloc((size_t)65536 * 256 * 2);   // 33.6 MB (level-local)
  bf16*  HsA  = (bf16*)alloc((size_t)32768 * 256 * 2);   // 16.8 MB
  bf16*  HsB  = (bf16*)alloc((size_t)32768 * 256 * 2);   // 16.8 MB
  bf16*  FCb  = (bf16*)alloc((size_t)32768 * 256 * 2);   // 16.8 MB (level 15)
  bf16*  C    = (bf16*)alloc((size_t)65536 * 256 * 2);   // 33.6 MB (level-local)
  bf16*  H2   = (bf16*)alloc((size_t)16384 * 256 * 2);   // 8.4 MB (fused ping-pong)
  bf16*  C2   = (bf16*)alloc((size_t)16384 * 256 * 2);   // 8.4 MB

  prep_all<<<32768, 256, 0, stream>>>(X, Xb, Wioux, Wiouh, Wfx, Wfh,
                                      bioux, biouh, bfx, bfh,
                                      Wiou, Wf, biou, bfc);

  // Leaf level: K=256 (x only); writes C/H rows [0,65536), HsA [0,32768)
  iou_gemm<<<8 * 512, 256, 0, stream>>>(
      Xb, LEAF_START, HsA /*unused*/, nullptr, biou, Wiou,
      C, H, HsA, out, LEAF_COUNT, 256, 0);

  // Level 15 (two dispatches; 1-D swizzled grids).
  for (int lvl = 15; lvl > FUSE_TOP; --lvl) {
    const int count = 1 << lvl;
    const int s = count - 1;
    const int M2 = 2 * count;
    const bf16* Hsin = (lvl & 1) ? HsA : HsB;
    bf16* Hsout      = (lvl & 1) ? HsB : HsA;
    f_gemm<<<2 * (M2 / 128), 256, 0, stream>>>(
        Xb, s, H, C, bfc, Wf, FCb, M2);
    iou_gemm<<<8 * (count / 128), 256, 0, stream>>>(
        Xb, s, Hsin, FCb, biou, Wiou, C, H, Hsout, out, count, 512, 0);
  }

  // Fused levels 14..0: one dispatch per level; H/C ping-pong between the
  // big level-local buffers and the small H2/C2 pair.
  for (int lvl = FUSE_TOP; lvl >= 0; --lvl) {
    const int count = 1 << lvl;
    const int s = count - 1;
    const bf16* Hsin = (lvl & 1) ? HsA : HsB;
    bf16* Hsout      = (lvl & 1) ? HsB : HsA;
    const int pp = (FUSE_TOP - lvl) & 1;     // 0: in=H,C out=H2,C2 ; 1: reverse
    const bf16* Hin = pp ? H2 : H;
    const bf16* Cin = pp ? C2 : C;
    bf16* Hout      = pp ? H  : H2;
    bf16* Cout      = pp ? C  : C2;
    fused_level<<<8 * ((count + 127) / 128), 256, 0, stream>>>(
        Xb, s, Hin, Cin, Hsin, biou, bfc, Wiou, Wf,
        Hout, Cout, Hsout, out, count, lvl == 0);
  }
}